// Round 1
// baseline (31.681 us; speedup 1.0000x reference)
//
#include <hip/hip_runtime.h>

// out[b,n,d] = (x@Wq+bq)[b,n,d] * kv[b,d],  kv[b,d] = sum_m ((x@Wk+bk)*(x@Wv+bv))[b,m,d]
// B=4, N=1024, D=128, fp32.
//
// R1 restructure vs previous best (23.7 us):
//  - W streams via VMEM (global_load_dwordx4 / vmcnt) instead of the scalar
//    pipe.  s_load returns out-of-order on lgkmcnt and the old loop mixed
//    s_load + ds_read on that one counter -> per-k-group lgkmcnt(0) drains
//    -> VALUBusy 6%.  vmcnt is in-order and pipelines across the fully
//    unrolled K loop.
//  - Split: K1 computes only k,v and per-rowtile kv partials (no q write);
//    K2 reduces the 16 partials and computes q fused with the kv scale.
//    Removes the 6 MB q round-trip + the memory-bound scale kernel.
//  - XCD-aware swizzle: the 8 col-group blocks sharing one x-tile get the
//    same (blockIdx % 8) -> same XCD -> x fetched once per tile
//    (FETCH 8.4 MB -> ~2.5 MB), and K2 re-reads x as an L2 hit.
//  - LDS x-tile stride 130 -> 132 floats: rows stay 16B-aligned, x read as
//    one ds_read_b128 per 4 k at the bank floor (8 slots, conflict-free).

#define BB 4
#define NN 1024
#define DD 128
#define RT 64              // rows per block
#define NRT (NN / RT)      // 16 rowtiles per batch
#define XST 132            // LDS row stride in floats (132 % 4 == 0, banks at floor)

static __device__ __forceinline__ void fma4(float4& a, float s, float4 m) {
    a.x = fmaf(s, m.x, a.x);
    a.y = fmaf(s, m.y, a.y);
    a.z = fmaf(s, m.z, a.z);
    a.w = fmaf(s, m.w, a.w);
}

// swizzled decode: blocks i, i+64, ..., i+448 (same low-3 bits) share one
// (b,t) x-tile and land on the same XCD under round-robin dispatch.
static __device__ __forceinline__ void decode_blk(int i, int& b, int& t, int& cg) {
    cg = i >> 6;                               // 0..7 col-group
    const int g = ((i >> 3) & 7) * 8 + (i & 7); // 0..63 tile group
    b = g >> 4;
    t = g & 15;
}

static __device__ __forceinline__ void stage_x(const float* __restrict__ x,
                                               int b, int t, int tid, float* xs) {
    const float4* src = reinterpret_cast<const float4*>(
        x + ((size_t)b * NN + (size_t)t * RT) * DD);
#pragma unroll
    for (int j = 0; j < 8; ++j) {
        const int idx = tid + j * 256;          // 0..2047 float4s, coalesced
        const float4 v = src[idx];
        const int r = idx >> 5, kq = idx & 31;  // row, float4-within-row
        *reinterpret_cast<float4*>(&xs[r * XST + kq * 4]) = v;
    }
}

// K1: k,v projections for a 64-row tile; butterfly-reduce k*v over the rows;
// write one float4 partial per (b,t,cw).
__global__ __launch_bounds__(256, 2) void kv_kernel(
    const float* __restrict__ x,
    const float* __restrict__ Wk, const float* __restrict__ bk,
    const float* __restrict__ Wv, const float* __restrict__ bv,
    float* __restrict__ partials)
{
    __shared__ float xs[RT * XST];              // 33.8 KB
    int b, t, cg;
    decode_blk(blockIdx.x, b, t, cg);
    const int tid = threadIdx.x;

    stage_x(x, b, t, tid, xs);
    __syncthreads();

    const int lane = tid & 63;                  // lane == row within tile
    const int w    = tid >> 6;
    const int cw   = (cg << 2) + w;             // float4-column 0..31 (wave-uniform value, VGPR-held)

    const float4* Wk4 = reinterpret_cast<const float4*>(Wk) + cw;
    const float4* Wv4 = reinterpret_cast<const float4*>(Wv) + cw;

    float4 ka = {0.f, 0.f, 0.f, 0.f};
    float4 va = {0.f, 0.f, 0.f, 0.f};
    const float* xrow = &xs[lane * XST];

#pragma unroll
    for (int k0 = 0; k0 < DD; k0 += 4) {
        const float4 xv = *reinterpret_cast<const float4*>(&xrow[k0]);
        fma4(ka, xv.x, Wk4[(k0 + 0) * 32]);
        fma4(va, xv.x, Wv4[(k0 + 0) * 32]);
        fma4(ka, xv.y, Wk4[(k0 + 1) * 32]);
        fma4(va, xv.y, Wv4[(k0 + 1) * 32]);
        fma4(ka, xv.z, Wk4[(k0 + 2) * 32]);
        fma4(va, xv.z, Wv4[(k0 + 2) * 32]);
        fma4(ka, xv.w, Wk4[(k0 + 3) * 32]);
        fma4(va, xv.w, Wv4[(k0 + 3) * 32]);
    }

    const float4 bk4 = reinterpret_cast<const float4*>(bk)[cw];
    const float4 bv4 = reinterpret_cast<const float4*>(bv)[cw];

    float4 p;
    p.x = (ka.x + bk4.x) * (va.x + bv4.x);
    p.y = (ka.y + bk4.y) * (va.y + bv4.y);
    p.z = (ka.z + bk4.z) * (va.z + bv4.z);
    p.w = (ka.w + bk4.w) * (va.w + bv4.w);
#pragma unroll
    for (int off = 1; off < 64; off <<= 1) {
        p.x += __shfl_xor(p.x, off);
        p.y += __shfl_xor(p.y, off);
        p.z += __shfl_xor(p.z, off);
        p.w += __shfl_xor(p.w, off);
    }
    if (lane == 0)
        reinterpret_cast<float4*>(partials)[((size_t)b * NRT + t) * 32 + cw] = p;
}

// K2: reduce the 16 rowtile partials (fixed order) -> kv, then q projection
// fused with the kv scale.  Same tile/swizzle as K1 so x is an L2 hit.
__global__ __launch_bounds__(256, 2) void q_kernel(
    const float* __restrict__ x,
    const float* __restrict__ Wq, const float* __restrict__ bq,
    const float* __restrict__ partials,
    float* __restrict__ out)
{
    __shared__ float xs[RT * XST];
    int b, t, cg;
    decode_blk(blockIdx.x, b, t, cg);
    const int tid = threadIdx.x;

    stage_x(x, b, t, tid, xs);

    const int lane = tid & 63;
    const int w    = tid >> 6;
    const int cw   = (cg << 2) + w;

    // kv reduce: 16 uniform float4 loads, fixed order (deterministic)
    float4 kv = {0.f, 0.f, 0.f, 0.f};
    {
        const float4* p4 = reinterpret_cast<const float4*>(partials)
                         + (size_t)b * NRT * 32 + cw;
#pragma unroll
        for (int j = 0; j < NRT; ++j) {
            const float4 pv = p4[(size_t)j * 32];
            kv.x += pv.x; kv.y += pv.y; kv.z += pv.z; kv.w += pv.w;
        }
    }
    __syncthreads();

    const float4* Wq4 = reinterpret_cast<const float4*>(Wq) + cw;
    float4 qa = {0.f, 0.f, 0.f, 0.f};
    const float* xrow = &xs[lane * XST];

#pragma unroll
    for (int k0 = 0; k0 < DD; k0 += 4) {
        const float4 xv = *reinterpret_cast<const float4*>(&xrow[k0]);
        fma4(qa, xv.x, Wq4[(k0 + 0) * 32]);
        fma4(qa, xv.y, Wq4[(k0 + 1) * 32]);
        fma4(qa, xv.z, Wq4[(k0 + 2) * 32]);
        fma4(qa, xv.w, Wq4[(k0 + 3) * 32]);
    }

    const float4 bq4 = reinterpret_cast<const float4*>(bq)[cw];
    float4 o;
    o.x = (qa.x + bq4.x) * kv.x;
    o.y = (qa.y + bq4.y) * kv.y;
    o.z = (qa.z + bq4.z) * kv.z;
    o.w = (qa.w + bq4.w) * kv.w;
    reinterpret_cast<float4*>(
        out + ((size_t)b * NN + (size_t)t * RT + lane) * DD)[cw] = o;
}

extern "C" void kernel_launch(void* const* d_in, const int* in_sizes, int n_in,
                              void* d_out, int out_size, void* d_ws, size_t ws_size,
                              hipStream_t stream) {
    const float* x  = (const float*)d_in[0];
    const float* Wq = (const float*)d_in[1];
    const float* bq = (const float*)d_in[2];
    const float* Wk = (const float*)d_in[3];
    const float* bk = (const float*)d_in[4];
    const float* Wv = (const float*)d_in[5];
    const float* bv = (const float*)d_in[6];
    float* out      = (float*)d_out;
    float* partials = (float*)d_ws;   // 4*16*128 floats = 32 KB

    kv_kernel<<<dim3(BB * NRT * 8), dim3(256), 0, stream>>>(
        x, Wk, bk, Wv, bv, partials);
    q_kernel<<<dim3(BB * NRT * 8), dim3(256), 0, stream>>>(
        x, Wq, bq, partials, out);
}